// Round 6
// baseline (63.887 us; speedup 1.0000x reference)
//
#include <hip/hip_runtime.h>

using u32 = unsigned int;

typedef __attribute__((ext_vector_type(8))) _Float16 f16x8;
typedef __attribute__((ext_vector_type(4))) float    f32x4;

// ---------------------------------------------------------------------------
// prep: WcatT[n][kk] = s(i,kb) * W[c][(i^kb)*256 + u]   (f16, 1024x1024)
// sign bits packed: bit (4*i + kb) of 0x3950
// ---------------------------------------------------------------------------
__global__ __launch_bounds__(256) void build_wcatT(const float* __restrict__ W,
                                                   _Float16* __restrict__ Wt) {
    int t  = blockIdx.x * 256 + threadIdx.x;
    int n  = t >> 10, kk = t & 1023;
    int kb = n >> 8,  u  = n & 255;
    int i  = kk >> 8, c  = kk & 255;
    int j  = i ^ kb;
    float v = W[c * 1024 + j * 256 + u];
    if ((0x3950u >> (i * 4 + kb)) & 1u) v = -v;
    Wt[t] = (_Float16)v;
}

// ---------------------------------------------------------------------------
// GEMM, fused f32->f16 A-cast. BM=128, BN=128, BK=32, 3-deep LDS (48KB),
// 4 waves (2M x 2N, 64x64 each), 256 thr, grid 1024 -> 2-3 blocks/CU.
// One 16-MFMA phase + ONE barrier per tile; counted VMW(6), distance-2.
// Reg cap 256 (launch_bounds(256,2)) => provably no spills (vmcnt-safe).
// ---------------------------------------------------------------------------
__device__ __forceinline__ void async16(const void* g, void* l) {
    __builtin_amdgcn_global_load_lds((const __attribute__((address_space(1))) u32*)g,
                                     (__attribute__((address_space(3))) u32*)l,
                                     16, 0, 0);
}

#define BARRIER() do { asm volatile("" ::: "memory"); \
                       __builtin_amdgcn_s_barrier(); \
                       asm volatile("" ::: "memory"); } while (0)

#define VMW(n)  asm volatile("s_waitcnt vmcnt(" #n ")" ::: "memory")
#define LGKM0() asm volatile("s_waitcnt lgkmcnt(0)" ::: "memory")
#define SB0()   __builtin_amdgcn_sched_barrier(0)

#define GL16(dst, ptr, off) \
    asm volatile("global_load_dwordx4 %0, %1, off offset:" #off \
                 : "=v"(dst) : "v"(ptr))

#define MFMA(av, bv, c) __builtin_amdgcn_mfma_f32_16x16x32_f16(av, bv, c, 0, 0, 0)

#define PHASE16() do { \
    __builtin_amdgcn_s_setprio(1); \
    acc[0][0]=MFMA(af0,bf0,acc[0][0]); acc[0][1]=MFMA(af0,bf1,acc[0][1]); \
    acc[0][2]=MFMA(af0,bf2,acc[0][2]); acc[0][3]=MFMA(af0,bf3,acc[0][3]); \
    acc[1][0]=MFMA(af1,bf0,acc[1][0]); acc[1][1]=MFMA(af1,bf1,acc[1][1]); \
    acc[1][2]=MFMA(af1,bf2,acc[1][2]); acc[1][3]=MFMA(af1,bf3,acc[1][3]); \
    acc[2][0]=MFMA(af2,bf0,acc[2][0]); acc[2][1]=MFMA(af2,bf1,acc[2][1]); \
    acc[2][2]=MFMA(af2,bf2,acc[2][2]); acc[2][3]=MFMA(af2,bf3,acc[2][3]); \
    acc[3][0]=MFMA(af3,bf0,acc[3][0]); acc[3][1]=MFMA(af3,bf1,acc[3][1]); \
    acc[3][2]=MFMA(af3,bf2,acc[3][2]); acc[3][3]=MFMA(af3,bf3,acc[3][3]); \
    __builtin_amdgcn_s_setprio(0); \
    __builtin_amdgcn_sched_barrier(0); \
} while (0)

// issue A f32 loads for K-tile U: 16 f32 (64B) per thread -> 4 regs
#define ISSUE_A(U, d0, d1, d2, d3) do { \
    const float* _p = pA + (size_t)((U) >> 3) * 4194304 + ((U) & 7) * 32; \
    GL16(d0, _p, 0); GL16(d1, _p, 16); GL16(d2, _p, 32); GL16(d3, _p, 48); \
} while (0)

// stage B K-tile U into buf SB (2 x gload_lds/thread, src pre-swizzled)
#define STAGE_B(U, SB) do { \
    async16(gB0 + (U) * 32, lds + (SB) * 8192 + 4096 + tid * 8); \
    async16(gB1 + (U) * 32, lds + (SB) * 8192 + 6144 + tid * 8); \
} while (0)

// cvt 16 f32 -> f16, two swizzled ds_write_b128 into buf WBUF's A region
#define WRITE_A(WBUF, s0, s1, s2, s3) do { \
    f16x8 h0, h1; \
    h0[0]=(_Float16)(s0)[0]; h0[1]=(_Float16)(s0)[1]; \
    h0[2]=(_Float16)(s0)[2]; h0[3]=(_Float16)(s0)[3]; \
    h0[4]=(_Float16)(s1)[0]; h0[5]=(_Float16)(s1)[1]; \
    h0[6]=(_Float16)(s1)[2]; h0[7]=(_Float16)(s1)[3]; \
    h1[0]=(_Float16)(s2)[0]; h1[1]=(_Float16)(s2)[1]; \
    h1[2]=(_Float16)(s2)[2]; h1[3]=(_Float16)(s2)[3]; \
    h1[4]=(_Float16)(s3)[0]; h1[5]=(_Float16)(s3)[1]; \
    h1[6]=(_Float16)(s3)[2]; h1[7]=(_Float16)(s3)[3]; \
    _Float16* _wp = lds + (WBUF) * 8192; \
    *(f16x8*)(_wp + awoff0) = h0; \
    *(f16x8*)(_wp + awoff1) = h1; \
} while (0)

// tile T: read buf BUF; issue A/B(T+2); 16 MFMA; gate; write A(T+1); barrier
#define TILE(T, BUF, SBUF, WBUF, DO_ISSUE, I0,I1,I2,I3, DO_WRITE, W0,W1,W2,W3, GATE) do { \
    const _Float16* Ab = lds + (BUF) * 8192; \
    f16x8 af0, af1, af2, af3, bf0, bf1, bf2, bf3; \
    af0 = *(const f16x8*)(Ab + aoff);        af1 = *(const f16x8*)(Ab + aoff + 512); \
    af2 = *(const f16x8*)(Ab + aoff + 1024); af3 = *(const f16x8*)(Ab + aoff + 1536); \
    bf0 = *(const f16x8*)(Ab + boff);        bf1 = *(const f16x8*)(Ab + boff + 512); \
    bf2 = *(const f16x8*)(Ab + boff + 1024); bf3 = *(const f16x8*)(Ab + boff + 1536); \
    if (DO_ISSUE) { ISSUE_A((T) + 2, I0, I1, I2, I3); STAGE_B((T) + 2, SBUF); } \
    PHASE16(); \
    GATE; \
    SB0(); \
    if (DO_WRITE) { WRITE_A(WBUF, W0, W1, W2, W3); } \
    LGKM0(); \
    BARRIER(); \
} while (0)

__global__ __launch_bounds__(256, 2) void ga_gemm(const float* __restrict__ A,    // x f32
                                                  const _Float16* __restrict__ Bt,// WcatT
                                                  const float*  __restrict__ bias,
                                                  float* __restrict__ out) {
    __shared__ _Float16 lds[3 * 8192] __attribute__((aligned(16)));  // 48 KiB

    const int tid  = threadIdx.x;
    const int lane = tid & 63;
    const int wid  = tid >> 6;          // 0..3
    const int wm   = wid >> 1;          // 0..1  (M half, 64 rows)
    const int wn   = wid & 1;           // 0..1  (N half, 64 cols)
    const int l15  = lane & 15;
    const int lg   = lane >> 4;

    // swizzle: xcd = bid&7; consecutive idx on an XCD share one A m-panel
    const int bid = blockIdx.x;               // 0..1023
    const int xcd = bid & 7, idx = bid >> 3;  // idx 0..127
    const int nt  = idx & 7;                  // 8 n-tiles
    const int mt  = (idx >> 3) * 8 + xcd;     // 128 m-tiles
    const int m0  = mt * 128, n0 = nt * 128;

    // A reg-staging: thread -> row ar (0..127), half ah (16 f32 = 64B)
    const int ar = tid >> 1, ah = tid & 1;
    const float* pA = A + (size_t)(m0 + ar) * 256 + ah * 16;
    const int aph = (ar >> 1) & 3;            // swizzle phase
    const int awoff0 = ar * 32 + ((ah * 2)     ^ aph) * 8;  // f16 units
    const int awoff1 = ar * 32 + ((ah * 2 + 1) ^ aph) * 8;

    // B staging (chunk q -> row q>>2, chunk q&3; source pre-swizzled)
    const int br = tid >> 2;
    const int bg = (tid & 3) ^ ((br >> 1) & 3);
    const _Float16* gB0 = Bt + (size_t)(n0 + br) * 1024 + bg * 8;
    const _Float16* gB1 = gB0 + 64 * 1024;    // rows +64, same swizzle phase

    // ds_read fragment offsets (f16 units); B region at +4096
    const int sc   = lg ^ ((l15 >> 1) & 3);
    const int aoff = (wm * 64 + l15) * 32 + sc * 8;
    const int boff = 4096 + (wn * 64 + l15) * 32 + sc * 8;

    f32x4 acc[4][4] = {};
    f32x4 u0, u1, u2, u3, v0, v1, v2, v3;

    // prologue: A0->u, B0->buf0; A1->v, B1->buf1; write A0; enter loop
    ISSUE_A(0, u0, u1, u2, u3);  STAGE_B(0, 0);
    ISSUE_A(1, v0, v1, v2, v3);  STAGE_B(1, 1);
    VMW(6);  SB0();               // drains A0,B0 (leaves A1,B1 in flight)
    WRITE_A(0, u0, u1, u2, u3);
    LGKM0();
    BARRIER();

    // tiles 0..29: even -> issue u / write v; odd -> issue v / write u
    for (int t = 0; t < 30; t += 6) {
        TILE(t + 0, 0, 2, 1, 1, u0,u1,u2,u3, 1, v0,v1,v2,v3, VMW(6));
        TILE(t + 1, 1, 0, 2, 1, v0,v1,v2,v3, 1, u0,u1,u2,u3, VMW(6));
        TILE(t + 2, 2, 1, 0, 1, u0,u1,u2,u3, 1, v0,v1,v2,v3, VMW(6));
        TILE(t + 3, 0, 2, 1, 1, v0,v1,v2,v3, 1, u0,u1,u2,u3, VMW(6));
        TILE(t + 4, 1, 0, 2, 1, u0,u1,u2,u3, 1, v0,v1,v2,v3, VMW(6));
        TILE(t + 5, 2, 1, 0, 1, v0,v1,v2,v3, 1, u0,u1,u2,u3, VMW(6));
    }
    TILE(30, 0, 0, 1, 0, u0,u1,u2,u3, 1, v0,v1,v2,v3, VMW(0));  // write A31
    TILE(31, 1, 0, 0, 0, u0,u1,u2,u3, 0, u0,u1,u2,u3, (void)0);

    // epilogue: C/D layout col=lane&15, row=(lane>>4)*4+r
    const int kb   = nt >> 1;                         // output blade
    const int ucol = (nt & 1) * 128 + wn * 64 + l15;  // col within blade
    float bv[4];
#pragma unroll
    for (int fn = 0; fn < 4; ++fn) bv[fn] = bias[nt * 128 + wn * 64 + fn * 16 + l15];
#pragma unroll
    for (int fm = 0; fm < 4; ++fm) {
        const int m = m0 + wm * 64 + fm * 16 + lg * 4;
#pragma unroll
        for (int r = 0; r < 4; ++r) {
            float* op = out + ((size_t)kb * 16384 + m + r) * 256 + ucol;
#pragma unroll
            for (int fn = 0; fn < 4; ++fn)
                op[fn * 16] = acc[fm][fn][r] + bv[fn];
        }
    }
}

// ---------------------------------------------------------------------------
extern "C" void kernel_launch(void* const* d_in, const int* in_sizes, int n_in,
                              void* d_out, int out_size, void* d_ws, size_t ws_size,
                              hipStream_t stream) {
    (void)in_sizes; (void)n_in; (void)out_size; (void)ws_size;
    const float* x = (const float*)d_in[0];   // (65536, 256)
    const float* W = (const float*)d_in[1];   // (256, 1024)
    const float* b = (const float*)d_in[2];   // (1024,)
    float* out = (float*)d_out;               // (65536, 256)

    _Float16* Wt = (_Float16*)d_ws;           // 2 MB

    build_wcatT<<<4096, 256, 0, stream>>>(W, Wt);
    ga_gemm<<<1024, 256, 0, stream>>>(x, Wt, b, out);
}

// Round 7
// 60.482 us; speedup vs baseline: 1.0563x; 1.0563x over previous
//
#include <hip/hip_runtime.h>

using u32 = unsigned int;

typedef __attribute__((ext_vector_type(8))) _Float16 f16x8;
typedef __attribute__((ext_vector_type(4))) float    f32x4;

// ---------------------------------------------------------------------------
// prep: WcatT[n][kk] = s(i,kb) * W[c][(i^kb)*256 + u]   (f16, 1024x1024)
// sign bits packed: bit (4*i + kb) of 0x3950
// ---------------------------------------------------------------------------
__global__ __launch_bounds__(256) void build_wcatT(const float* __restrict__ W,
                                                   _Float16* __restrict__ Wt) {
    int t  = blockIdx.x * 256 + threadIdx.x;
    int n  = t >> 10, kk = t & 1023;
    int kb = n >> 8,  u  = n & 255;
    int i  = kk >> 8, c  = kk & 255;
    int j  = i ^ kb;
    float v = W[c * 1024 + j * 256 + u];
    if ((0x3950u >> (i * 4 + kb)) & 1u) v = -v;
    Wt[t] = (_Float16)v;
}

// ---------------------------------------------------------------------------
// GEMM, fused f32->f16 A-cast.  M=16384 N=1024 K=1024.
// 256x256 tile, BK=64, 2-buffer LDS (2 x 64KB), 8 waves (2M x 4N),
// ONE barrier per K-tile, 4 x 16-MFMA setprio clusters, counted vmcnt:
//   A: reg-staged distance-2 (8 GL16 -> 16 cvt pairs -> 4 swizzled ds_write)
//   B: gload_lds distance-1 (4 async16, source pre-swizzled, linear dest)
// Swizzle (both sides): 64-f16 rows = 8 chunks of 16B; phys = logical ^ (row&7).
// ---------------------------------------------------------------------------
__device__ __forceinline__ void async16(const void* g, void* l) {
    __builtin_amdgcn_global_load_lds((const __attribute__((address_space(1))) u32*)g,
                                     (__attribute__((address_space(3))) u32*)l,
                                     16, 0, 0);
}

#define BARRIER() do { asm volatile("" ::: "memory"); \
                       __builtin_amdgcn_s_barrier(); \
                       asm volatile("" ::: "memory"); } while (0)

#define VMW(n)  asm volatile("s_waitcnt vmcnt(" #n ")" ::: "memory")
#define LGKM0() asm volatile("s_waitcnt lgkmcnt(0)" ::: "memory")
#define SB0()   __builtin_amdgcn_sched_barrier(0)

#define GL16(dst, ptr, off) \
    asm volatile("global_load_dwordx4 %0, %1, off offset:" #off \
                 : "=v"(dst) : "v"(ptr))

#define MFMA(av, bv, c) __builtin_amdgcn_mfma_f32_16x16x32_f16(av, bv, c, 0, 0, 0)

// 16-MFMA cluster: A frags a0..a3 (m-block MB..MB+3) x B frags B0..B3
#define CL16(MB, B0, B1, B2, B3) do { \
    __builtin_amdgcn_s_setprio(1); \
    acc[MB+0][0]=MFMA(a0,B0,acc[MB+0][0]); acc[MB+0][1]=MFMA(a0,B1,acc[MB+0][1]); \
    acc[MB+0][2]=MFMA(a0,B2,acc[MB+0][2]); acc[MB+0][3]=MFMA(a0,B3,acc[MB+0][3]); \
    acc[MB+1][0]=MFMA(a1,B0,acc[MB+1][0]); acc[MB+1][1]=MFMA(a1,B1,acc[MB+1][1]); \
    acc[MB+1][2]=MFMA(a1,B2,acc[MB+1][2]); acc[MB+1][3]=MFMA(a1,B3,acc[MB+1][3]); \
    acc[MB+2][0]=MFMA(a2,B0,acc[MB+2][0]); acc[MB+2][1]=MFMA(a2,B1,acc[MB+2][1]); \
    acc[MB+2][2]=MFMA(a2,B2,acc[MB+2][2]); acc[MB+2][3]=MFMA(a2,B3,acc[MB+2][3]); \
    acc[MB+3][0]=MFMA(a3,B0,acc[MB+3][0]); acc[MB+3][1]=MFMA(a3,B1,acc[MB+3][1]); \
    acc[MB+3][2]=MFMA(a3,B2,acc[MB+3][2]); acc[MB+3][3]=MFMA(a3,B3,acc[MB+3][3]); \
    __builtin_amdgcn_s_setprio(0); \
} while (0)

// issue 8 A f32 loads (128B contiguous) for K-tile U into s0..s7
#define ISSUE_A(U) do { \
    const float* _p = pA + (size_t)((U) >> 2) * 4194304 + ((U) & 3) * 64; \
    GL16(s0, _p, 0);  GL16(s1, _p, 16); GL16(s2, _p, 32);  GL16(s3, _p, 48); \
    GL16(s4, _p, 64); GL16(s5, _p, 80); GL16(s6, _p, 96);  GL16(s7, _p, 112); \
} while (0)

// stage B K-tile U into buffer at f16-offset NB (4 async16, 64 rows each)
#define STAGE_B(U, NB) do { \
    const _Float16* _gb = gB + (U) * 64; \
    async16(_gb,          lds + (NB) + 16384 + tid * 8); \
    async16(_gb + 65536,  lds + (NB) + 20480 + tid * 8); \
    async16(_gb + 131072, lds + (NB) + 24576 + tid * 8); \
    async16(_gb + 196608, lds + (NB) + 28672 + tid * 8); \
} while (0)

// cvt s0..s7 (32 f32) -> 4 swizzled ds_write_b128 into buffer NB's A region
#define WRITE_A(NB) do { \
    f16x8 h0, h1, h2, h3; \
    h0[0]=(_Float16)s0[0]; h0[1]=(_Float16)s0[1]; h0[2]=(_Float16)s0[2]; h0[3]=(_Float16)s0[3]; \
    h0[4]=(_Float16)s1[0]; h0[5]=(_Float16)s1[1]; h0[6]=(_Float16)s1[2]; h0[7]=(_Float16)s1[3]; \
    h1[0]=(_Float16)s2[0]; h1[1]=(_Float16)s2[1]; h1[2]=(_Float16)s2[2]; h1[3]=(_Float16)s2[3]; \
    h1[4]=(_Float16)s3[0]; h1[5]=(_Float16)s3[1]; h1[6]=(_Float16)s3[2]; h1[7]=(_Float16)s3[3]; \
    h2[0]=(_Float16)s4[0]; h2[1]=(_Float16)s4[1]; h2[2]=(_Float16)s4[2]; h2[3]=(_Float16)s4[3]; \
    h2[4]=(_Float16)s5[0]; h2[5]=(_Float16)s5[1]; h2[6]=(_Float16)s5[2]; h2[7]=(_Float16)s5[3]; \
    h3[0]=(_Float16)s6[0]; h3[1]=(_Float16)s6[1]; h3[2]=(_Float16)s6[2]; h3[3]=(_Float16)s6[3]; \
    h3[4]=(_Float16)s7[0]; h3[5]=(_Float16)s7[1]; h3[6]=(_Float16)s7[2]; h3[7]=(_Float16)s7[3]; \
    _Float16* _wp = lds + (NB) + awbase; \
    *(f16x8*)(_wp + awo0) = h0;  *(f16x8*)(_wp + awo1) = h1; \
    *(f16x8*)(_wp + awo2) = h2;  *(f16x8*)(_wp + awo3) = h3; \
} while (0)

// 4 phases of one K-tile (reads buffer at f16-offset BUF)
#define PHASES(BUF) do { \
    const _Float16* Ab = lds + (BUF); \
    f16x8 a0, a1, a2, a3, b0, b1, b2, b3, b4, b5, b6, b7; \
    a0 = *(const f16x8*)(Ab + arow + c0);        a1 = *(const f16x8*)(Ab + arow + 1024 + c0); \
    a2 = *(const f16x8*)(Ab + arow + 2048 + c0); a3 = *(const f16x8*)(Ab + arow + 3072 + c0); \
    b0 = *(const f16x8*)(Ab + brow + c0);        b1 = *(const f16x8*)(Ab + brow + 1024 + c0); \
    b2 = *(const f16x8*)(Ab + brow + 2048 + c0); b3 = *(const f16x8*)(Ab + brow + 3072 + c0); \
    CL16(0, b0, b1, b2, b3); \
    a0 = *(const f16x8*)(Ab + arow + c1);        a1 = *(const f16x8*)(Ab + arow + 1024 + c1); \
    a2 = *(const f16x8*)(Ab + arow + 2048 + c1); a3 = *(const f16x8*)(Ab + arow + 3072 + c1); \
    b4 = *(const f16x8*)(Ab + brow + c1);        b5 = *(const f16x8*)(Ab + brow + 1024 + c1); \
    b6 = *(const f16x8*)(Ab + brow + 2048 + c1); b7 = *(const f16x8*)(Ab + brow + 3072 + c1); \
    CL16(0, b4, b5, b6, b7); \
    a0 = *(const f16x8*)(Ab + arow + 4096 + c0); a1 = *(const f16x8*)(Ab + arow + 5120 + c0); \
    a2 = *(const f16x8*)(Ab + arow + 6144 + c0); a3 = *(const f16x8*)(Ab + arow + 7168 + c0); \
    CL16(4, b0, b1, b2, b3); \
    a0 = *(const f16x8*)(Ab + arow + 4096 + c1); a1 = *(const f16x8*)(Ab + arow + 5120 + c1); \
    a2 = *(const f16x8*)(Ab + arow + 6144 + c1); a3 = *(const f16x8*)(Ab + arow + 7168 + c1); \
    CL16(4, b4, b5, b6, b7); \
} while (0)

__global__ __launch_bounds__(512, 2) void ga_gemm(const float* __restrict__ A,    // x f32
                                                  const _Float16* __restrict__ Bt,// WcatT
                                                  const float*  __restrict__ bias,
                                                  float* __restrict__ out) {
    __shared__ _Float16 lds[2 * 32768] __attribute__((aligned(16)));  // 128 KiB

    const int tid  = threadIdx.x;
    const int lane = tid & 63;
    const int wid  = tid >> 6;
    const int wm   = wid >> 2;          // 0..1
    const int wn   = wid & 3;           // 0..3
    const int l15  = lane & 15;
    const int lg   = lane >> 4;

    // XCD swizzle: 256 blocks, 32/XCD contiguous (8 m-panels x all 4 n)
    const int bid = blockIdx.x;
    const int swz = (bid & 7) * 32 + (bid >> 3);
    const int mt  = swz >> 2, nt = swz & 3;
    const int m0  = mt * 256,  n0 = nt * 256;

    // A reg-staging: thread -> row r (0..255), half h (32 f32 = 128B)
    const int r = tid >> 1, h = tid & 1;
    const float* pA = A + (size_t)(m0 + r) * 256 + h * 32;
    const int awbase = r * 64;                 // f16 units
    const int awsw   = r & 7;
    const int awo0 = (((h * 4 + 0) ^ awsw) << 3);
    const int awo1 = (((h * 4 + 1) ^ awsw) << 3);
    const int awo2 = (((h * 4 + 2) ^ awsw) << 3);
    const int awo3 = (((h * 4 + 3) ^ awsw) << 3);

    // B staging source (pre-swizzled; dest is linear via async16)
    const int brow0 = tid >> 3;
    const int blc   = (tid & 7) ^ (brow0 & 7);
    const _Float16* gB = Bt + (size_t)(n0 + brow0) * 1024 + blc * 8;

    // fragment ds_read offsets (f16 units); phys chunk = logical ^ (row&7)
    const int csw  = l15 & 7;
    const int c0   = ((lg)     ^ csw) * 8;     // kq=0
    const int c1   = ((4 + lg) ^ csw) * 8;     // kq=1
    const int arow = (wm * 128 + l15) * 64;
    const int brow = 16384 + (wn * 64 + l15) * 64;

    f32x4 acc[8][4] = {};
    f32x4 s0, s1, s2, s3, s4, s5, s6, s7;

    // prologue
    ISSUE_A(0);                         // 8 in flight
    STAGE_B(0, 0);                      // +4 = 12
    VMW(4); SB0();                      // A(0) drained (B(0) 4 left)
    WRITE_A(0);
    LGKM0();
    ISSUE_A(1);                         // B(0) 4 + A(1) 8
    VMW(8);                             // B(0) drained
    BARRIER();

    // steady tiles 0..13
    for (int t = 0; t < 14; ++t) {
        const int buf  = (t & 1) << 15;
        const int nbuf = buf ^ 32768;
        STAGE_B(t + 1, nbuf);           // A(t+1) 8 + B(t+1) 4
        PHASES(buf);
        VMW(4); SB0();                  // A(t+1) drained
        WRITE_A(nbuf);
        LGKM0();
        ISSUE_A(t + 2);                 // B(t+1) 4 + A(t+2) 8
        VMW(8);                         // B(t+1) drained
        BARRIER();
    }
    // t = 14: stage B(15); write A(15); no new A
    STAGE_B(15, 32768);
    PHASES(0);
    VMW(4); SB0();                      // A(15) drained
    WRITE_A(32768);
    LGKM0();
    VMW(0);                             // B(15) drained
    BARRIER();
    // t = 15
    PHASES(32768);

    // epilogue: C/D layout col=lane&15, row=(lane>>4)*4+rr; BN==blade size
    const size_t outBase = (size_t)nt * 16384 * 256;
    const int ucol = wn * 64 + l15;
    float bv[4];
#pragma unroll
    for (int fn = 0; fn < 4; ++fn) bv[fn] = bias[nt * 256 + ucol + fn * 16];
#pragma unroll
    for (int fm = 0; fm < 8; ++fm) {
        const int m = m0 + wm * 128 + fm * 16 + lg * 4;
#pragma unroll
        for (int rr = 0; rr < 4; ++rr) {
            float* op = out + outBase + (size_t)(m + rr) * 256;
#pragma unroll
            for (int fn = 0; fn < 4; ++fn)
                op[ucol + fn * 16] = acc[fm][fn][rr] + bv[fn];
        }
    }
}

// ---------------------------------------------------------------------------
extern "C" void kernel_launch(void* const* d_in, const int* in_sizes, int n_in,
                              void* d_out, int out_size, void* d_ws, size_t ws_size,
                              hipStream_t stream) {
    (void)in_sizes; (void)n_in; (void)out_size; (void)ws_size;
    const float* x = (const float*)d_in[0];   // (65536, 256)
    const float* W = (const float*)d_in[1];   // (256, 1024)
    const float* b = (const float*)d_in[2];   // (1024,)
    float* out = (float*)d_out;               // (65536, 256)

    _Float16* Wt = (_Float16*)d_ws;           // 2 MB

    build_wcatT<<<4096, 256, 0, stream>>>(W, Wt);
    ga_gemm<<<256, 512, 0, stream>>>(x, Wt, b, out);
}